// Round 1
// baseline (202.857 us; speedup 1.0000x reference)
//
#include <hip/hip_runtime.h>
#include <cstdint>

// Problem constants
#define BB 256
#define TT 128
#define DD 300
#define HH 16
#define GG 64     // 4*H
#define CC 5
#define NKS 10    // K-steps of 32 (300 padded to 320)
#define HSTR 68   // hsm row stride (bank-skewed: 64 -> 13-way conflict in ph3)
#define L2E 1.4426950408889634f

typedef __attribute__((ext_vector_type(8))) short short8;   // bf16x8 MFMA frag
typedef __attribute__((ext_vector_type(4))) float float4v;  // fp32x4 acc

// RNE fp32 -> bf16 bits
static __device__ inline unsigned short f2bf(float f) {
  unsigned u = __float_as_uint(f);
  return (unsigned short)((u + 0x7FFFu + ((u >> 16) & 1u)) >> 16);
}
static __device__ inline float bf2f(unsigned short h) {
  return __uint_as_float(((unsigned)h) << 16);
}

// ---------------------------------------------------------------------------
// 3-kernel decomposition (was: one fused kernel at 1 block/CU, 1 wave/SIMD):
//   K0 frag_build : W_ih -> global bf16 hi/lo B-fragments, ONCE (80 KB)
//   K1 lstm_gemm  : zero-LDS split-bf16 MFMA GEMM, 2048 waves (8 waves/CU),
//                   B-frags from L2-hot global buffer, emb gather depth-2
//                   pipelined; writes pre-scaled transposed xgT[b][gate][ts]
//   K2 lstm_rec   : 128-step serial recurrence (wave 0) + output projection
//
// d_ws layout: [0, 8388608)            xgT   float[256][64][128]
//              [8388608, +40960)       Bh_g  ushort[40*64*8]
//              [8429568, +40960)       Bl_g  ushort[40*64*8]
// All ws bytes written before read each iteration (poison-safe).
// ---------------------------------------------------------------------------

// ---- K0: build B-fragments. Block s (0..39) = one frag set, lane-mapped as
// the old ph0b: lane holds B[k=quad*8+j][n=lane&15], j=0..7. ----
__global__ __launch_bounds__(64) void frag_build_kernel(
    const float* __restrict__ W_ih,
    unsigned short* __restrict__ Bh_g, unsigned short* __restrict__ Bl_g) {
  const int s = blockIdx.x;      // 0..39
  const int lane = threadIdx.x;  // 0..63
  const int m = lane & 15, quad = lane >> 4;
  const int ks = s >> 2, nt = s & 3;
  const int c = nt * 16 + m;          // gate column 0..63
  const int k0 = ks * 32 + quad * 8;  // K offset
  float4 z4 = {0.f, 0.f, 0.f, 0.f};
  float4 w0 = z4, w1 = z4;
  // W_ih row stride 300 floats (1200 B, 16B-aligned); k0 multiple of 8.
  if (k0 + 4 <= DD) w0 = *(const float4*)&W_ih[c * DD + k0];
  if (k0 + 8 <= DD) w1 = *(const float4*)&W_ih[c * DD + k0 + 4];
  float wf[8] = {w0.x, w0.y, w0.z, w0.w, w1.x, w1.y, w1.z, w1.w};
  short8 h8, l8;
#pragma unroll
  for (int jj = 0; jj < 8; jj++) {
    unsigned short hb = f2bf(wf[jj]);
    h8[jj] = (short)hb;
    l8[jj] = (short)f2bf(wf[jj] - bf2f(hb));
  }
  const int base = (s * 64 + lane) * 8;
  *(short8*)&Bh_g[base] = h8;
  *(short8*)&Bl_g[base] = l8;
}

// ---- K1: MFMA GEMM. 512 blocks x 4 waves; wave = one 16-row M-tile.
// Block gb: batch b = gb>>1, timestep base (gb&1)*64 + w*16.
// No LDS, no __syncthreads; occupancy 2 blocks/CU = 8 waves/CU. ----
__global__ __launch_bounds__(256, 2) void lstm_gemm_kernel(
    const int* __restrict__ x, const float* __restrict__ emb,
    const unsigned short* __restrict__ Bh_g,
    const unsigned short* __restrict__ Bl_g,
    const float* __restrict__ b_ih, const float* __restrict__ b_hh,
    float* __restrict__ xgT) {
  const int t = threadIdx.x;
  const int gb = blockIdx.x;  // 0..511
  const int b = gb >> 1;
  const int w = t >> 6;
  const int lane = t & 63;
  const int m = lane & 15, quad = lane >> 4;
  const int tbase = (gb & 1) * 64 + w * 16;

  const int xr = x[b * TT + tbase + m];
  const float* __restrict__ arow = emb + (size_t)xr * DD + quad * 8;

  float4v acc[4];
#pragma unroll
  for (int nt = 0; nt < 4; nt++) acc[nt] = (float4v){0.f, 0.f, 0.f, 0.f};

  // Depth-2 rolling prefetch: pre[parity][half] = 4 float4 = 16 VGPRs.
  float4 pre[2][2];
  auto issue = [&](int ks) {
    if (ks < 9) {
      const int p = ks & 1;
      pre[p][0] = *(const float4*)(arow + ks * 32);
      pre[p][1] = *(const float4*)(arow + ks * 32 + 4);
    } else if (ks == 9) {
      // Tail: k0 = 288 + quad*8; guard each float4 (no OOB on last row)
      const int k0t = 288 + quad * 8;
      float4 z4 = {0.f, 0.f, 0.f, 0.f};
      pre[1][0] = (k0t + 4 <= DD) ? *(const float4*)(arow + 288) : z4;
      pre[1][1] = (k0t + 8 <= DD) ? *(const float4*)(arow + 292) : z4;
    }
  };
  issue(0);
  issue(1);

#pragma unroll
  for (int ks = 0; ks < NKS; ks++) {
    const int p = ks & 1;
    // Consume: convert this ks's A data to hi/lo bf16 fragments.
    short8 ah, al;
    {
      float af[8] = {pre[p][0].x, pre[p][0].y, pre[p][0].z, pre[p][0].w,
                     pre[p][1].x, pre[p][1].y, pre[p][1].z, pre[p][1].w};
#pragma unroll
      for (int jj = 0; jj < 8; jj++) {
        unsigned short hb = f2bf(af[jj]);
        ah[jj] = (short)hb;
        al[jj] = (short)f2bf(af[jj] - bf2f(hb));
      }
    }
    // Re-issue this parity slot for ks+2 (no-op past the end).
    issue(ks + 2);

#pragma unroll
    for (int nt = 0; nt < 4; nt++) {
      const int base = ((ks * 4 + nt) * 64 + lane) * 8;
      short8 bh = *(const short8*)&Bh_g[base];  // L2-hot, coalesced 16B/lane
      short8 bl = *(const short8*)&Bl_g[base];
      acc[nt] = __builtin_amdgcn_mfma_f32_16x16x32_bf16(ah, bh, acc[nt], 0, 0, 0);
      acc[nt] = __builtin_amdgcn_mfma_f32_16x16x32_bf16(al, bh, acc[nt], 0, 0, 0);
      acc[nt] = __builtin_amdgcn_mfma_f32_16x16x32_bf16(ah, bl, acc[nt], 0, 0, 0);
    }
  }

  // Epilogue: bias + per-gate pre-scale, transposed float4 store.
  // C/D layout: col=lane&15, row=quad*4+reg  [m89-verified].
#pragma unroll
  for (int nt = 0; nt < 4; nt++) {
    const int col = nt * 16 + m;
    const float scale = (nt == 2) ? (-2.0f * L2E) : (-L2E);
    const float bias = b_ih[col] + b_hh[col];
    float4 v;
    v.x = (acc[nt][0] + bias) * scale;
    v.y = (acc[nt][1] + bias) * scale;
    v.z = (acc[nt][2] + bias) * scale;
    v.w = (acc[nt][3] + bias) * scale;
    *(float4*)&xgT[(size_t)b * (TT * GG) + col * TT + tbase + quad * 4] = v;
  }
}

// ---- K2: recurrence (wave 0) + output projection. One block per batch. ----
__global__ __launch_bounds__(256, 1) void lstm_rec_kernel(
    const float* __restrict__ xg, const float* __restrict__ W_hh,
    const float* __restrict__ W_out, const float* __restrict__ b_out,
    float* __restrict__ out) {
  __shared__ float hsm[TT * HSTR];  // 34 KB, stride-68 bank-skewed

  const int t = threadIdx.x;
  const int b = blockIdx.x;
  const int lane = t & 63;

  // Lane mapping: k=lane>>2 (hidden unit), g=lane&3 (gate), j=g*16+k.
  if (t < 64) {
    const int k = lane >> 2;
    const int g = lane & 3;
    const int j = g * 16 + k;
    const float wscale = (g == 2) ? (-2.0f * L2E) : (-L2E);
    const float Aa = (g == 2) ? (-4.0f * L2E) : 1.0f;  // act = Aa*s + Ba
    const float Ba = (g == 2) ? (2.0f * L2E) : 0.0f;   // gate2 -> scaled tanh

    float wh[16];
#pragma unroll
    for (int kk = 0; kk < 16; kk++) wh[kk] = W_hh[j * HH + kk] * wscale;

    float cs = 0.0f;  // scaled cell state: cs = -2*L2E*c
    float hu[16];
#pragma unroll
    for (int kk = 0; kk < 16; kk++) hu[kk] = 0.0f;

    // Pre-scaled preacts from global (L2/L3-hot after K1), 2-chunk prefetch.
    const float* __restrict__ gptr = xg + (size_t)b * (TT * GG) + j * TT;
    float4 gA = *(const float4*)gptr;        // ts 0..3
    float4 gB = *(const float4*)(gptr + 4);  // ts 4..7

    for (int ch = 0; ch < 32; ch++) {
      float4 gC = (ch < 30) ? *(const float4*)(gptr + 4 * (ch + 2)) : gA;
      float ga[4] = {gA.x, gA.y, gA.z, gA.w};
#pragma unroll
      for (int s4 = 0; s4 < 4; s4++) {
        const int ts = ch * 4 + s4;
        // gv = scaled preact + h . wh  (4 split chains)
        float a0 = fmaf(hu[0], wh[0], ga[s4]);
        a0 = fmaf(hu[1], wh[1], a0);
        a0 = fmaf(hu[2], wh[2], a0);
        a0 = fmaf(hu[3], wh[3], a0);
        float a1 = hu[4] * wh[4];
        a1 = fmaf(hu[5], wh[5], a1);
        a1 = fmaf(hu[6], wh[6], a1);
        a1 = fmaf(hu[7], wh[7], a1);
        float a2 = hu[8] * wh[8];
        a2 = fmaf(hu[9], wh[9], a2);
        a2 = fmaf(hu[10], wh[10], a2);
        a2 = fmaf(hu[11], wh[11], a2);
        float a3 = hu[12] * wh[12];
        a3 = fmaf(hu[13], wh[13], a3);
        a3 = fmaf(hu[14], wh[14], a3);
        a3 = fmaf(hu[15], wh[15], a3);
        float gv = (a0 + a1) + (a2 + a3);

        float e = __builtin_amdgcn_exp2f(gv);
        float s = __builtin_amdgcn_rcpf(1.0f + e);
        float act = fmaf(Aa, s, Ba);  // sigmoid, or -2L2E*tanh for gate 2

        int ai = __float_as_int(act);
        float iv = __int_as_float(__builtin_amdgcn_update_dpp(ai, ai, 0x00, 0xF, 0xF, true));
        float fv = __int_as_float(__builtin_amdgcn_update_dpp(ai, ai, 0x55, 0xF, 0xF, true));
        float gs = __int_as_float(__builtin_amdgcn_update_dpp(ai, ai, 0xAA, 0xF, 0xF, true));
        float ov = __int_as_float(__builtin_amdgcn_update_dpp(ai, ai, 0xFF, 0xF, 0xF, true));

        cs = fmaf(fv, cs, iv * gs);  // scaled-domain cell update
        float e2 = __builtin_amdgcn_exp2f(cs);
        float tc = fmaf(2.0f, __builtin_amdgcn_rcpf(1.0f + e2), -1.0f);  // tanh(c)
        float hnew = ov * tc;  // quad-uniform

        hsm[ts * HSTR + lane] = hnew;  // all lanes store (no exec toggle)

#pragma unroll
        for (int kk = 0; kk < 16; kk++)
          hu[kk] = __uint_as_float(
              __builtin_amdgcn_readlane(__float_as_uint(hnew), 4 * kk));
      }
      gA = gB;
      gB = gC;
    }
  }
  __syncthreads();

  // Output projection (all 256 threads)
  float* outb = out + (size_t)b * TT * CC;
  for (int idx = t; idx < TT * CC; idx += 256) {
    int tt2 = idx / CC;
    int cc = idx - tt2 * CC;
    const float* wr = W_out + cc * HH;
    float accv = b_out[cc];
#pragma unroll
    for (int kk = 0; kk < 16; kk++)
      accv = fmaf(hsm[tt2 * HSTR + 4 * kk], wr[kk], accv);
    outb[idx] = accv;
  }
}

// ---------------------------------------------------------------------------
extern "C" void kernel_launch(void* const* d_in, const int* in_sizes, int n_in,
                              void* d_out, int out_size, void* d_ws, size_t ws_size,
                              hipStream_t stream) {
  const int*   x     = (const int*)d_in[0];
  const float* emb   = (const float*)d_in[1];
  const float* W_ih  = (const float*)d_in[2];
  const float* W_hh  = (const float*)d_in[3];
  const float* b_ih  = (const float*)d_in[4];
  const float* b_hh  = (const float*)d_in[5];
  const float* W_out = (const float*)d_in[6];
  const float* b_out = (const float*)d_in[7];
  float* out = (float*)d_out;

  // Workspace partition
  float* xgT = (float*)d_ws;                                   // 8,388,608 B
  unsigned short* Bh_g =
      (unsigned short*)((char*)d_ws + (size_t)BB * TT * GG * 4);  // 40,960 B
  unsigned short* Bl_g = Bh_g + NKS * 4 * 64 * 8;                 // 40,960 B

  frag_build_kernel<<<40, 64, 0, stream>>>(W_ih, Bh_g, Bl_g);
  lstm_gemm_kernel<<<512, 256, 0, stream>>>(x, emb, Bh_g, Bl_g, b_ih, b_hh, xgT);
  lstm_rec_kernel<<<BB, 256, 0, stream>>>(xgT, W_hh, W_out, b_out, out);
}

// Round 2
// 201.899 us; speedup vs baseline: 1.0047x; 1.0047x over previous
//
#include <hip/hip_runtime.h>
#include <cstdint>

// Problem constants
#define BB 256
#define TT 128
#define DD 300
#define HH 16
#define GG 64     // 4*H
#define CC 5
#define NKS 10    // K-steps of 32 (300 padded to 320)
#define HSTR 68   // hsm row stride (bank-skewed: 64 -> 13-way conflict in ph3)
#define L2E 1.4426950408889634f

typedef __attribute__((ext_vector_type(8))) short short8;   // bf16x8 MFMA frag
typedef __attribute__((ext_vector_type(4))) float float4v;  // fp32x4 acc

// RNE fp32 -> bf16 bits
static __device__ inline unsigned short f2bf(float f) {
  unsigned u = __float_as_uint(f);
  return (unsigned short)((u + 0x7FFFu + ((u >> 16) & 1u)) >> 16);
}
static __device__ inline float bf2f(unsigned short h) {
  return __uint_as_float(((unsigned)h) << 16);
}

// ---------------------------------------------------------------------------
// 2-kernel decomposition (round-1 had 3; K0's 40-block frag build + its launch
// cost more than building frags per-block in K1's LDS prologue):
//   K1 lstm_gemm : 512 blocks x 256 thr, LDS = 80KB (Bh 40K + Bl 40K)
//                  -> 2 blocks/CU, 8 waves/CU.
//                  prologue: issue cold emb prefetches FIRST, then build all
//                  40 hi/lo bf16 B-frag sets from W_ih (L2-hot) into LDS.
//                  main: split-bf16 3-MFMA GEMM, frags from LDS (was: global
//                  re-read of 164MB through L2), depth-2 emb gather pipeline.
//                  writes pre-scaled transposed xgT[b][gate][ts].
//   K2 lstm_rec  : 128-step serial recurrence (wave 0) + output projection.
//
// d_ws layout: [0, 8388608) xgT float[256][64][128]. All bytes written before
// read each iteration (poison-safe).
// ---------------------------------------------------------------------------

// ---- K1: MFMA GEMM. Wave = one 16-row M-tile.
// Block gb: batch b = gb>>1, timestep base (gb&1)*64 + w*16. ----
__global__ __launch_bounds__(256, 2) void lstm_gemm_kernel(
    const int* __restrict__ x, const float* __restrict__ emb,
    const float* __restrict__ W_ih,
    const float* __restrict__ b_ih, const float* __restrict__ b_hh,
    float* __restrict__ xgT) {
  __shared__ unsigned short Bh[NKS * 4 * 64 * 8];  // 40 KB
  __shared__ unsigned short Bl[NKS * 4 * 64 * 8];  // 40 KB

  const int t = threadIdx.x;
  const int gb = blockIdx.x;  // 0..511
  const int b = gb >> 1;
  const int w = t >> 6;
  const int lane = t & 63;
  const int m = lane & 15, quad = lane >> 4;
  const int tbase = (gb & 1) * 64 + w * 16;

  // Issue the cold embedding-row prefetches FIRST so their HBM latency hides
  // under the frag-build prologue.
  const int xr = x[b * TT + tbase + m];
  const float* __restrict__ arow = emb + (size_t)xr * DD + quad * 8;

  // Depth-2 rolling prefetch: pre[parity][half] = 4 float4 = 16 VGPRs.
  float4 pre[2][2];
  auto issue = [&](int ks) {
    if (ks < 9) {
      const int p = ks & 1;
      pre[p][0] = *(const float4*)(arow + ks * 32);
      pre[p][1] = *(const float4*)(arow + ks * 32 + 4);
    } else if (ks == 9) {
      // Tail: k0 = 288 + quad*8; guard each float4 (no OOB on last row)
      const int k0t = 288 + quad * 8;
      float4 z4 = {0.f, 0.f, 0.f, 0.f};
      pre[1][0] = (k0t + 4 <= DD) ? *(const float4*)(arow + 288) : z4;
      pre[1][1] = (k0t + 8 <= DD) ? *(const float4*)(arow + 292) : z4;
    }
  };
  issue(0);
  issue(1);

  // ---- Prologue: build B-frags from W_ih (global, L2-resident 76.8KB).
  // Wave w builds sets 10w..10w+9. Frag layout (16x16x32 B): lane holds
  // B[k=quad*8+j][n=lane&15], j=0..7. ----
  for (int si = 0; si < 10; si++) {
    const int s = w * 10 + si;
    const int ks = s >> 2, nt = s & 3;
    const int c = nt * 16 + m;          // gate column 0..63
    const int k0 = ks * 32 + quad * 8;  // K offset
    float4 z4 = {0.f, 0.f, 0.f, 0.f};
    float4 w0 = z4, w1 = z4;
    if (k0 + 4 <= DD) w0 = *(const float4*)&W_ih[c * DD + k0];
    if (k0 + 8 <= DD) w1 = *(const float4*)&W_ih[c * DD + k0 + 4];
    float wf[8] = {w0.x, w0.y, w0.z, w0.w, w1.x, w1.y, w1.z, w1.w};
    short8 h8, l8;
#pragma unroll
    for (int jj = 0; jj < 8; jj++) {
      unsigned short hb = f2bf(wf[jj]);
      h8[jj] = (short)hb;
      l8[jj] = (short)f2bf(wf[jj] - bf2f(hb));
    }
    const int base = (s * 64 + lane) * 8;
    *(short8*)&Bh[base] = h8;
    *(short8*)&Bl[base] = l8;
  }
  __syncthreads();

  float4v acc[4];
#pragma unroll
  for (int nt = 0; nt < 4; nt++) acc[nt] = (float4v){0.f, 0.f, 0.f, 0.f};

#pragma unroll
  for (int ks = 0; ks < NKS; ks++) {
    const int p = ks & 1;
    // Consume: convert this ks's A data to hi/lo bf16 fragments.
    short8 ah, al;
    {
      float af[8] = {pre[p][0].x, pre[p][0].y, pre[p][0].z, pre[p][0].w,
                     pre[p][1].x, pre[p][1].y, pre[p][1].z, pre[p][1].w};
#pragma unroll
      for (int jj = 0; jj < 8; jj++) {
        unsigned short hb = f2bf(af[jj]);
        ah[jj] = (short)hb;
        al[jj] = (short)f2bf(af[jj] - bf2f(hb));
      }
    }
    // Re-issue this parity slot for ks+2 (no-op past the end).
    issue(ks + 2);

#pragma unroll
    for (int nt = 0; nt < 4; nt++) {
      const int base = ((ks * 4 + nt) * 64 + lane) * 8;
      short8 bh = *(const short8*)&Bh[base];  // LDS, conflict-free b128
      short8 bl = *(const short8*)&Bl[base];
      acc[nt] = __builtin_amdgcn_mfma_f32_16x16x32_bf16(ah, bh, acc[nt], 0, 0, 0);
      acc[nt] = __builtin_amdgcn_mfma_f32_16x16x32_bf16(al, bh, acc[nt], 0, 0, 0);
      acc[nt] = __builtin_amdgcn_mfma_f32_16x16x32_bf16(ah, bl, acc[nt], 0, 0, 0);
    }
  }

  // Epilogue: bias + per-gate pre-scale, transposed float4 store.
  // C/D layout: col=lane&15, row=quad*4+reg  [m89-verified].
#pragma unroll
  for (int nt = 0; nt < 4; nt++) {
    const int col = nt * 16 + m;
    const float scale = (nt == 2) ? (-2.0f * L2E) : (-L2E);
    const float bias = b_ih[col] + b_hh[col];
    float4 v;
    v.x = (acc[nt][0] + bias) * scale;
    v.y = (acc[nt][1] + bias) * scale;
    v.z = (acc[nt][2] + bias) * scale;
    v.w = (acc[nt][3] + bias) * scale;
    *(float4*)&xgT[(size_t)b * (TT * GG) + col * TT + tbase + quad * 4] = v;
  }
}

// ---- K2: recurrence (wave 0) + output projection. One block per batch. ----
__global__ __launch_bounds__(256, 1) void lstm_rec_kernel(
    const float* __restrict__ xg, const float* __restrict__ W_hh,
    const float* __restrict__ W_out, const float* __restrict__ b_out,
    float* __restrict__ out) {
  __shared__ float hsm[TT * HSTR];  // 34 KB, stride-68 bank-skewed

  const int t = threadIdx.x;
  const int b = blockIdx.x;
  const int lane = t & 63;

  // Lane mapping: k=lane>>2 (hidden unit), g=lane&3 (gate), j=g*16+k.
  if (t < 64) {
    const int k = lane >> 2;
    const int g = lane & 3;
    const int j = g * 16 + k;
    const float wscale = (g == 2) ? (-2.0f * L2E) : (-L2E);
    const float Aa = (g == 2) ? (-4.0f * L2E) : 1.0f;  // act = Aa*s + Ba
    const float Ba = (g == 2) ? (2.0f * L2E) : 0.0f;   // gate2 -> scaled tanh

    float wh[16];
#pragma unroll
    for (int kk = 0; kk < 16; kk++) wh[kk] = W_hh[j * HH + kk] * wscale;

    float cs = 0.0f;  // scaled cell state: cs = -2*L2E*c
    float hu[16];
#pragma unroll
    for (int kk = 0; kk < 16; kk++) hu[kk] = 0.0f;

    // Pre-scaled preacts from global (L2-hot after K1), 2-chunk prefetch.
    const float* __restrict__ gptr = xg + (size_t)b * (TT * GG) + j * TT;
    float4 gA = *(const float4*)gptr;        // ts 0..3
    float4 gB = *(const float4*)(gptr + 4);  // ts 4..7

    for (int ch = 0; ch < 32; ch++) {
      float4 gC = (ch < 30) ? *(const float4*)(gptr + 4 * (ch + 2)) : gA;
      float ga[4] = {gA.x, gA.y, gA.z, gA.w};
#pragma unroll
      for (int s4 = 0; s4 < 4; s4++) {
        const int ts = ch * 4 + s4;
        // gv = scaled preact + h . wh  (4 split chains)
        float a0 = fmaf(hu[0], wh[0], ga[s4]);
        a0 = fmaf(hu[1], wh[1], a0);
        a0 = fmaf(hu[2], wh[2], a0);
        a0 = fmaf(hu[3], wh[3], a0);
        float a1 = hu[4] * wh[4];
        a1 = fmaf(hu[5], wh[5], a1);
        a1 = fmaf(hu[6], wh[6], a1);
        a1 = fmaf(hu[7], wh[7], a1);
        float a2 = hu[8] * wh[8];
        a2 = fmaf(hu[9], wh[9], a2);
        a2 = fmaf(hu[10], wh[10], a2);
        a2 = fmaf(hu[11], wh[11], a2);
        float a3 = hu[12] * wh[12];
        a3 = fmaf(hu[13], wh[13], a3);
        a3 = fmaf(hu[14], wh[14], a3);
        a3 = fmaf(hu[15], wh[15], a3);
        float gv = (a0 + a1) + (a2 + a3);

        float e = __builtin_amdgcn_exp2f(gv);
        float s = __builtin_amdgcn_rcpf(1.0f + e);
        float act = fmaf(Aa, s, Ba);  // sigmoid, or -2L2E*tanh for gate 2

        int ai = __float_as_int(act);
        float iv = __int_as_float(__builtin_amdgcn_update_dpp(ai, ai, 0x00, 0xF, 0xF, true));
        float fv = __int_as_float(__builtin_amdgcn_update_dpp(ai, ai, 0x55, 0xF, 0xF, true));
        float gs = __int_as_float(__builtin_amdgcn_update_dpp(ai, ai, 0xAA, 0xF, 0xF, true));
        float ov = __int_as_float(__builtin_amdgcn_update_dpp(ai, ai, 0xFF, 0xF, 0xF, true));

        cs = fmaf(fv, cs, iv * gs);  // scaled-domain cell update
        float e2 = __builtin_amdgcn_exp2f(cs);
        float tc = fmaf(2.0f, __builtin_amdgcn_rcpf(1.0f + e2), -1.0f);  // tanh(c)
        float hnew = ov * tc;  // quad-uniform

        hsm[ts * HSTR + lane] = hnew;  // all lanes store (no exec toggle)

#pragma unroll
        for (int kk = 0; kk < 16; kk++)
          hu[kk] = __uint_as_float(
              __builtin_amdgcn_readlane(__float_as_uint(hnew), 4 * kk));
      }
      gA = gB;
      gB = gC;
    }
  }
  __syncthreads();

  // Output projection (all 256 threads)
  float* outb = out + (size_t)b * TT * CC;
  for (int idx = t; idx < TT * CC; idx += 256) {
    int tt2 = idx / CC;
    int cc = idx - tt2 * CC;
    const float* wr = W_out + cc * HH;
    float accv = b_out[cc];
#pragma unroll
    for (int kk = 0; kk < 16; kk++)
      accv = fmaf(hsm[tt2 * HSTR + 4 * kk], wr[kk], accv);
    outb[idx] = accv;
  }
}

// ---------------------------------------------------------------------------
extern "C" void kernel_launch(void* const* d_in, const int* in_sizes, int n_in,
                              void* d_out, int out_size, void* d_ws, size_t ws_size,
                              hipStream_t stream) {
  const int*   x     = (const int*)d_in[0];
  const float* emb   = (const float*)d_in[1];
  const float* W_ih  = (const float*)d_in[2];
  const float* W_hh  = (const float*)d_in[3];
  const float* b_ih  = (const float*)d_in[4];
  const float* b_hh  = (const float*)d_in[5];
  const float* W_out = (const float*)d_in[6];
  const float* b_out = (const float*)d_in[7];
  float* out = (float*)d_out;

  float* xgT = (float*)d_ws;  // 8,388,608 B

  lstm_gemm_kernel<<<512, 256, 0, stream>>>(x, emb, W_ih, b_ih, b_hh, xgT);
  lstm_rec_kernel<<<BB, 256, 0, stream>>>(xgT, W_hh, W_out, b_out, out);
}

// Round 3
// 196.197 us; speedup vs baseline: 1.0339x; 1.0291x over previous
//
#include <hip/hip_runtime.h>
#include <cstdint>

// Problem constants
#define BB 256
#define TT 128
#define DD 300
#define HH 16
#define GG 64     // 4*H
#define CC 5
#define NKS 10    // K-steps of 32 (300 padded to 320)
#define XSTR 132  // xgsT row stride in floats (16B-aligned, bank-skewed)
#define HSTR 68   // hsm row stride (64 -> all-lanes-same-bank in projection)
#define L2E 1.4426950408889634f

typedef __attribute__((ext_vector_type(8))) short short8;   // bf16x8 MFMA frag
typedef __attribute__((ext_vector_type(4))) float float4v;  // fp32x4 acc

// RNE fp32 -> bf16 bits
static __device__ inline unsigned short f2bf(float f) {
  unsigned u = __float_as_uint(f);
  return (unsigned short)((u + 0x7FFFu + ((u >> 16) & 1u)) >> 16);
}
static __device__ inline float bf2f(unsigned short h) {
  return __uint_as_float(((unsigned)h) << 16);
}

// ---------------------------------------------------------------------------
// Single fused kernel (R0 structure — the best measured — minus its two known
// inefficiencies):
//   - NO rawW staging copy: B-frags built straight from global W_ih while the
//     cold embedding-row prefetches (issued FIRST) are in flight. One fewer
//     barrier, no LDS union.
//   - hsm stride 68 (was 64: every projection read hit one bank, ~13-way).
// Phases: [issue emb prefetch] -> frag build -> GEMM (split-bf16 3-MFMA,
//         depth-2 pipeline) -> xgsT (LDS) -> wave-0 recurrence -> projection.
// LDS: Bh 40K + Bl 40K + xgsT 33K + hsm 34K = 147 KB, 1 block/CU, 256 blocks.
// d_ws unused.
// ---------------------------------------------------------------------------
__global__ __launch_bounds__(256, 1) void lstm_fused_kernel(
    const int* __restrict__ x, const float* __restrict__ emb,
    const float* __restrict__ W_ih, const float* __restrict__ W_hh,
    const float* __restrict__ b_ih, const float* __restrict__ b_hh,
    const float* __restrict__ W_out, const float* __restrict__ b_out,
    float* __restrict__ out) {

  __shared__ unsigned short Bh[NKS * 4 * 64 * 8];  // 40 KB
  __shared__ unsigned short Bl[NKS * 4 * 64 * 8];  // 40 KB
  __shared__ float xgsT[GG * XSTR];                // 33 KB  [gate][ts]
  __shared__ float hsm[TT * HSTR];                 // 34 KB  [ts][lane]

  const int t = threadIdx.x;
  const int b = blockIdx.x;
  const int w = t >> 6;
  const int lane = t & 63;
  const int m = lane & 15, quad = lane >> 4;

  // ---- Issue the cold embedding-row prefetches FIRST: their ~900-cycle HBM
  // latency hides under the frag-build VALU work below. ----
  const int xr0 = x[b * TT + w * 32 + m];
  const int xr1 = x[b * TT + w * 32 + 16 + m];
  const float* __restrict__ arow0 = emb + (size_t)xr0 * DD + quad * 8;
  const float* __restrict__ arow1 = emb + (size_t)xr1 * DD + quad * 8;

  // Depth-2 rolling prefetch: pre[parity][row][half] = 8 float4 = 32 VGPRs.
  float4 pre[2][2][2];
  auto issue = [&](int ks) {
    if (ks < 9) {
      const int p = ks & 1;
      pre[p][0][0] = *(const float4*)(arow0 + ks * 32);
      pre[p][0][1] = *(const float4*)(arow0 + ks * 32 + 4);
      pre[p][1][0] = *(const float4*)(arow1 + ks * 32);
      pre[p][1][1] = *(const float4*)(arow1 + ks * 32 + 4);
    } else if (ks == 9) {
      // Tail: k0 = 288 + quad*8; guard each float4 (no OOB reads on last row)
      const int k0t = 288 + quad * 8;
      float4 z4 = {0.f, 0.f, 0.f, 0.f};
      pre[1][0][0] = (k0t + 4 <= DD) ? *(const float4*)(arow0 + 288) : z4;
      pre[1][0][1] = (k0t + 8 <= DD) ? *(const float4*)(arow0 + 292) : z4;
      pre[1][1][0] = (k0t + 4 <= DD) ? *(const float4*)(arow1 + 288) : z4;
      pre[1][1][1] = (k0t + 8 <= DD) ? *(const float4*)(arow1 + 292) : z4;
    }
  };
  issue(0);
  issue(1);

  // ---- Frag build from global W_ih (76.8 KB, L2/L3-served). Wave w builds
  // sets 10w..10w+9. Frag layout (16x16x32 B): lane holds
  // B[k=quad*8+j][n=lane&15], j=0..7. ----
  for (int si = 0; si < 10; si++) {
    const int s = w * 10 + si;
    const int ks = s >> 2, nt = s & 3;
    const int c = nt * 16 + m;          // gate column 0..63
    const int k0 = ks * 32 + quad * 8;  // K offset
    float4 z4 = {0.f, 0.f, 0.f, 0.f};
    float4 w0 = z4, w1 = z4;
    if (k0 + 4 <= DD) w0 = *(const float4*)&W_ih[c * DD + k0];
    if (k0 + 8 <= DD) w1 = *(const float4*)&W_ih[c * DD + k0 + 4];
    float wf[8] = {w0.x, w0.y, w0.z, w0.w, w1.x, w1.y, w1.z, w1.w};
    short8 h8, l8;
#pragma unroll
    for (int jj = 0; jj < 8; jj++) {
      unsigned short hb = f2bf(wf[jj]);
      h8[jj] = (short)hb;
      l8[jj] = (short)f2bf(wf[jj] - bf2f(hb));
    }
    const int base = (s * 64 + lane) * 8;
    *(short8*)&Bh[base] = h8;
    *(short8*)&Bl[base] = l8;
  }
  __syncthreads();

  // ---- GEMM: wave w covers timestep-rows w*32..w*32+31 (2 M-tiles). ----
  {
    float4v acc[2][4];
#pragma unroll
    for (int mt = 0; mt < 2; mt++)
#pragma unroll
      for (int nt = 0; nt < 4; nt++) acc[mt][nt] = (float4v){0.f, 0.f, 0.f, 0.f};

#pragma unroll
    for (int ks = 0; ks < NKS; ks++) {
      const int p = ks & 1;
      // Consume: convert this ks's A data to hi/lo bf16 fragments.
      short8 ah[2], al[2];
#pragma unroll
      for (int mt = 0; mt < 2; mt++) {
        float af[8] = {pre[p][mt][0].x, pre[p][mt][0].y, pre[p][mt][0].z,
                       pre[p][mt][0].w, pre[p][mt][1].x, pre[p][mt][1].y,
                       pre[p][mt][1].z, pre[p][mt][1].w};
#pragma unroll
        for (int jj = 0; jj < 8; jj++) {
          unsigned short hb = f2bf(af[jj]);
          ah[mt][jj] = (short)hb;
          al[mt][jj] = (short)f2bf(af[jj] - bf2f(hb));
        }
      }
      // Re-issue this parity slot for ks+2 (no-op past the end).
      issue(ks + 2);

#pragma unroll
      for (int nt = 0; nt < 4; nt++) {
        const int base = ((ks * 4 + nt) * 64 + lane) * 8;
        short8 bh = *(const short8*)&Bh[base];
        short8 bl = *(const short8*)&Bl[base];
#pragma unroll
        for (int mt = 0; mt < 2; mt++) {
          acc[mt][nt] = __builtin_amdgcn_mfma_f32_16x16x32_bf16(ah[mt], bh, acc[mt][nt], 0, 0, 0);
          acc[mt][nt] = __builtin_amdgcn_mfma_f32_16x16x32_bf16(al[mt], bh, acc[mt][nt], 0, 0, 0);
          acc[mt][nt] = __builtin_amdgcn_mfma_f32_16x16x32_bf16(ah[mt], bl, acc[mt][nt], 0, 0, 0);
        }
      }
    }

    // Epilogue: bias + per-gate pre-scale, TRANSPOSED store: xgsT[gate][ts].
    // C/D layout: col=lane&15, row=quad*4+reg  [m89-verified].
#pragma unroll
    for (int nt = 0; nt < 4; nt++) {
      const int col = nt * 16 + m;
      const float scale = (nt == 2) ? (-2.0f * L2E) : (-L2E);
      const float bias = b_ih[col] + b_hh[col];
#pragma unroll
      for (int mt = 0; mt < 2; mt++) {
#pragma unroll
        for (int reg = 0; reg < 4; reg++) {
          const int ts = w * 32 + mt * 16 + quad * 4 + reg;
          xgsT[col * XSTR + ts] = (acc[mt][nt][reg] + bias) * scale;
        }
      }
    }
  }
  __syncthreads();

  // ---- Recurrence (wave 0). Lane: k=lane>>2, g=lane&3, j=g*16+k ----
  if (t < 64) {
    const int k = lane >> 2;
    const int g = lane & 3;
    const int j = g * 16 + k;
    const float wscale = (g == 2) ? (-2.0f * L2E) : (-L2E);
    const float Aa = (g == 2) ? (-4.0f * L2E) : 1.0f;   // act = Aa*s + Ba
    const float Ba = (g == 2) ? (2.0f * L2E) : 0.0f;    // gate2 -> scaled tanh

    float wh[16];
#pragma unroll
    for (int kk = 0; kk < 16; kk++) wh[kk] = W_hh[j * HH + kk] * wscale;

    float cs = 0.0f;   // scaled cell state: cs = -2*L2E*c
    float hu[16];
#pragma unroll
    for (int kk = 0; kk < 16; kk++) hu[kk] = 0.0f;

    const float* __restrict__ gptr = &xgsT[j * XSTR];
    float4 gA = *(const float4*)gptr;        // ts 0..3
    float4 gB = *(const float4*)(gptr + 4);  // ts 4..7

    for (int ch = 0; ch < 32; ch++) {
      float4 gC = (ch < 30) ? *(const float4*)(gptr + 4 * (ch + 2)) : gA;
      float ga[4] = {gA.x, gA.y, gA.z, gA.w};
#pragma unroll
      for (int s4 = 0; s4 < 4; s4++) {
        const int ts = ch * 4 + s4;
        // gv = scaled preact + h . wh  (4 split chains)
        float a0 = fmaf(hu[0], wh[0], ga[s4]);
        a0 = fmaf(hu[1], wh[1], a0);
        a0 = fmaf(hu[2], wh[2], a0);
        a0 = fmaf(hu[3], wh[3], a0);
        float a1 = hu[4] * wh[4];
        a1 = fmaf(hu[5], wh[5], a1);
        a1 = fmaf(hu[6], wh[6], a1);
        a1 = fmaf(hu[7], wh[7], a1);
        float a2 = hu[8] * wh[8];
        a2 = fmaf(hu[9], wh[9], a2);
        a2 = fmaf(hu[10], wh[10], a2);
        a2 = fmaf(hu[11], wh[11], a2);
        float a3 = hu[12] * wh[12];
        a3 = fmaf(hu[13], wh[13], a3);
        a3 = fmaf(hu[14], wh[14], a3);
        a3 = fmaf(hu[15], wh[15], a3);
        float gv = (a0 + a1) + (a2 + a3);

        float e = __builtin_amdgcn_exp2f(gv);
        float s = __builtin_amdgcn_rcpf(1.0f + e);
        float act = fmaf(Aa, s, Ba);   // sigmoid, or -2L2E*tanh for gate 2

        int ai = __float_as_int(act);
        float iv = __int_as_float(__builtin_amdgcn_update_dpp(ai, ai, 0x00, 0xF, 0xF, true));
        float fv = __int_as_float(__builtin_amdgcn_update_dpp(ai, ai, 0x55, 0xF, 0xF, true));
        float gs = __int_as_float(__builtin_amdgcn_update_dpp(ai, ai, 0xAA, 0xF, 0xF, true));
        float ov = __int_as_float(__builtin_amdgcn_update_dpp(ai, ai, 0xFF, 0xF, 0xF, true));

        cs = fmaf(fv, cs, iv * gs);    // scaled-domain cell update
        float e2 = __builtin_amdgcn_exp2f(cs);
        float tc = fmaf(2.0f, __builtin_amdgcn_rcpf(1.0f + e2), -1.0f);  // tanh(c)
        float hnew = ov * tc;          // quad-uniform

        hsm[ts * HSTR + lane] = hnew;  // all lanes store (no exec toggle)

#pragma unroll
        for (int kk = 0; kk < 16; kk++)
          hu[kk] = __uint_as_float(
              __builtin_amdgcn_readlane(__float_as_uint(hnew), 4 * kk));
      }
      gA = gB; gB = gC;
    }
  }
  __syncthreads();

  // ---- Output projection (all 256 threads) ----
  float* outb = out + (size_t)b * TT * CC;
  for (int idx = t; idx < TT * CC; idx += 256) {
    int tt2 = idx / CC;
    int cc = idx - tt2 * CC;
    const float* wr = W_out + cc * HH;
    float accv = b_out[cc];
#pragma unroll
    for (int kk = 0; kk < 16; kk++)
      accv = fmaf(hsm[tt2 * HSTR + 4 * kk], wr[kk], accv);
    outb[idx] = accv;
  }
}

// ---------------------------------------------------------------------------
extern "C" void kernel_launch(void* const* d_in, const int* in_sizes, int n_in,
                              void* d_out, int out_size, void* d_ws, size_t ws_size,
                              hipStream_t stream) {
  const int*   x     = (const int*)d_in[0];
  const float* emb   = (const float*)d_in[1];
  const float* W_ih  = (const float*)d_in[2];
  const float* W_hh  = (const float*)d_in[3];
  const float* b_ih  = (const float*)d_in[4];
  const float* b_hh  = (const float*)d_in[5];
  const float* W_out = (const float*)d_in[6];
  const float* b_out = (const float*)d_in[7];
  float* out = (float*)d_out;

  lstm_fused_kernel<<<BB, 256, 0, stream>>>(x, emb, W_ih, W_hh, b_ih, b_hh,
                                            W_out, b_out, out);
}